// Round 1
// baseline (278.821 us; speedup 1.0000x reference)
//
#include <hip/hip_runtime.h>
#include <math.h>

// Problem constants (reference shapes are fixed)
constexpr int Bc = 8, Cc = 64, Hc = 256, Wc = 256, Sc = 4;
constexpr int NPATCH = Bc * (Hc / Sc) * (Wc / Sc);  // 32768
constexpr int TP = 8;                               // patches per block (32-col strip)

// Tile T[c][r][col0..31]: float4-aligned pitches. CP % 32 == 20 -> for b128 ops each
// lane-octet's 4-bank spans {20c%32} cover all 32 banks (conflict-free per phase).
constexpr int RP = 36;                  // row pitch (32 data + 4 pad), mult of 4
constexpr int CP = 4 * RP + 4;          // 148
constexpr int TILE_F = Cc * CP;         // 9472 floats = 37888 B

// Phase-2 overlay into S (tile is dead after the v-load barrier):
constexpr int FCW_P   = 66;             // even pitch -> float2 reads; banks (2c+k)%32 = 2-way (free)
constexpr int FCW_OFF = 0;              // 64*66 = 4224 floats
constexpr int PIX_P   = 68;             // mult-of-4 pitch -> b128 reads, 2-way (free)
constexpr int PIX_OFF = Cc * FCW_P;     // 4224
constexpr int PIX_W   = 16 * PIX_P;     // 1088 floats per wave
static_assert(PIX_OFF + 4 * PIX_W <= TILE_F, "overlay must fit inside tile");

__device__ __forceinline__ float sigmoidf_(float v) {
    return 1.0f / (1.0f + __expf(-v));
}

// 256 threads (4 waves), 8 patches/block. LDS = 37888 + 2048 = 39936 B -> 4 blocks/CU
// (16 waves/CU, 2x the previous version). Barriers: 3 (was 6); all per-wave LDS
// round-trips use intra-wave s_waitcnt fences (wave = scheduling quantum, DS in-order).
__global__ __launch_bounds__(256, 4)
void ciam_kernel(const float* __restrict__ x,
                 const float* __restrict__ fc_w,
                 const float* __restrict__ fc_b,
                 const float* __restrict__ c1w,
                 const float* __restrict__ c1b,
                 const float* __restrict__ c2w,
                 const float* __restrict__ c2b,
                 float* __restrict__ out)
{
    __shared__ __align__(16) float S[TILE_F];        // tile, then fcw+pixbuf overlay
    __shared__ __align__(16) float maxbuf[TP][64];   // per-patch channel maxes

    const int tid  = threadIdx.x;
    const int gid  = blockIdx.x;
    const int b    = gid >> 9;          // 512 blocks per batch (64 ph x 8 pwg)
    const int rem  = gid & 511;
    const int ph   = rem >> 3;
    const int pwg  = rem & 7;
    const int col0 = pwg * 32;

    // ---- Issue tile loads (coalesced float4; 8 in flight per thread) ----
    float4 tl[8];
    #pragma unroll
    for (int i = 0; i < 8; ++i) {
        const int u = i * 256 + tid;
        const int seg = u >> 3, c_ = seg >> 2, r_ = seg & 3, j4 = (u & 7) << 2;
        tl[i] = *reinterpret_cast<const float4*>(
            x + (((size_t)(b * Cc + c_) * Hc + (ph * Sc + r_)) * Wc + col0 + j4));
    }
    // ---- Prefetch fc_w into registers (consumed after B2; latency hidden by stage-in) ----
    float4 wl[4];
    #pragma unroll
    for (int i = 0; i < 4; ++i) {
        const int u = i * 256 + tid;
        const int row = u >> 4, jf = (u & 15) << 2;
        wl[i] = *reinterpret_cast<const float4*>(fc_w + row * 64 + jf);
    }
    const float fb  = fc_b[tid & 63];
    const float w10 = c1w[0], w11 = c1w[1], b1 = c1b[0];
    const float w20 = c2w[0], w21 = c2w[1], b2 = c2b[0];

    // ---- Tile -> LDS: one ds_write_b128 per iter, bank-conflict-free ----
    #pragma unroll
    for (int i = 0; i < 8; ++i) {
        const int u = i * 256 + tid;
        const int seg = u >> 3, c_ = seg >> 2, r_ = seg & 3, j4 = (u & 7) << 2;
        *reinterpret_cast<float4*>(&S[c_ * CP + r_ * RP + j4]) = tl[i];
    }
    __syncthreads();                                   // B1: tile ready

    const int wave = tid >> 6, lane = tid & 63, c = lane;
    const int p0 = wave * 2;                           // this wave's two patches

    // ---- v-load: 8 x ds_read_b128 per lane (lane = channel) ----
    float v[2][16];
    #pragma unroll
    for (int pi = 0; pi < 2; ++pi) {
        const float* tp = &S[c * CP + (p0 + pi) * 4];
        #pragma unroll
        for (int r = 0; r < 4; ++r) {
            const float4 q4 = *reinterpret_cast<const float4*>(tp + r * RP);
            v[pi][r*4+0] = q4.x; v[pi][r*4+1] = q4.y;
            v[pi][r*4+2] = q4.z; v[pi][r*4+3] = q4.w;
        }
    }

    // ---- Channel attention input: per-channel max over patch pixels ----
    float mx0 = -3.4e38f, mx1 = -3.4e38f;
    #pragma unroll
    for (int t = 0; t < 16; ++t) {
        mx0 = fmaxf(mx0, v[0][t]);
        mx1 = fmaxf(mx1, v[1][t]);
    }
    maxbuf[p0][c]     = mx0;
    maxbuf[p0 + 1][c] = mx1;
    __syncthreads();                                   // B2: tile fully consumed, S reusable

    // ---- Overlay-stage fc_w (regs were loaded at kernel start) ----
    #pragma unroll
    for (int i = 0; i < 4; ++i) {
        const int u = i * 256 + tid;
        const int row = u >> 4, jf = (u & 15) << 2;
        float* fd = &S[FCW_OFF + row * FCW_P + jf];
        fd[0] = wl[i].x; fd[1] = wl[i].y; fd[2] = wl[i].z; fd[3] = wl[i].w;
    }
    __syncthreads();                                   // B3: fc_w ready

    // ---- FC (64x64 GEMV x2) -> sigmoid -> scale ----
    const float* wrow = &S[FCW_OFF + c * FCW_P];
    const float* m0r  = maxbuf[p0];
    const float* m1r  = maxbuf[p0 + 1];
    float a0 = fb, a1 = fb;
    #pragma unroll 8
    for (int k2 = 0; k2 < 32; ++k2) {
        const float2 wv = *reinterpret_cast<const float2*>(wrow + 2 * k2);
        const float2 q0 = *reinterpret_cast<const float2*>(m0r + 2 * k2);   // broadcast
        const float2 q1 = *reinterpret_cast<const float2*>(m1r + 2 * k2);   // broadcast
        a0 = fmaf(wv.x, q0.x, a0); a0 = fmaf(wv.y, q0.y, a0);
        a1 = fmaf(wv.x, q1.x, a1); a1 = fmaf(wv.y, q1.y, a1);
    }
    const float m0 = sigmoidf_(a0), m1 = sigmoidf_(a1);
    #pragma unroll
    for (int t = 0; t < 16; ++t) { v[0][t] *= m0; v[1][t] *= m1; }

    // ---- Per-pixel + per-patch gates (all intra-wave from here; no more barriers) ----
    float* PB = &S[PIX_OFF + wave * PIX_W];
    const int a_ = lane >> 2, q_ = lane & 3;           // 4 lanes per pixel, 16 ch each
    const float* pbr = PB + a_ * PIX_P + q_ * 16;

    #pragma unroll
    for (int pi = 0; pi < 2; ++pi) {
        // pixel-major transpose (private per-wave region; stride-1 writes, 2-way banks)
        #pragma unroll
        for (int t = 0; t < 16; ++t)
            PB[t * PIX_P + c] = v[pi][t];
        __asm__ volatile("s_waitcnt lgkmcnt(0)" ::: "memory");  // wave-local fence

        float s = 0.f, mxp = -3.4e38f;
        #pragma unroll
        for (int t4 = 0; t4 < 4; ++t4) {
            const float4 u4 = *reinterpret_cast<const float4*>(pbr + 4 * t4);
            s += (u4.x + u4.y) + (u4.z + u4.w);
            mxp = fmaxf(mxp, fmaxf(fmaxf(u4.x, u4.y), fmaxf(u4.z, u4.w)));
        }
        s += __shfl_xor(s, 1);
        s += __shfl_xor(s, 2);
        mxp = fmaxf(mxp, __shfl_xor(mxp, 1));
        mxp = fmaxf(mxp, __shfl_xor(mxp, 2));
        const float g1 = sigmoidf_(w10 * (s * (1.f / 64.f)) + w11 * mxp + b1);

        // Patch gate directly from pixel stats: sum_a g1_a*s_a, max_a g1_a*mx_a (g1>0).
        float ts = g1 * s, tm = g1 * mxp;
        #pragma unroll
        for (int off = 4; off <= 32; off <<= 1) {
            ts += __shfl_xor(ts, off);
            tm  = fmaxf(tm, __shfl_xor(tm, off));
        }
        const float g2 = sigmoidf_(w20 * (ts * (1.f / 1024.f)) + w21 * tm + b2);

        // Gather per-pixel g1 (constant-lane shfl -> readlane) and store from registers.
        const size_t obase = ((size_t)(b * Cc + c) * Hc + ph * Sc) * Wc + col0 + (p0 + pi) * 4;
        #pragma unroll
        for (int r = 0; r < 4; ++r) {
            float4 o;
            o.x = v[pi][r*4+0] * (__shfl(g1, (r*4+0) << 2) * g2);
            o.y = v[pi][r*4+1] * (__shfl(g1, (r*4+1) << 2) * g2);
            o.z = v[pi][r*4+2] * (__shfl(g1, (r*4+2) << 2) * g2);
            o.w = v[pi][r*4+3] * (__shfl(g1, (r*4+3) << 2) * g2);
            *reinterpret_cast<float4*>(out + obase + (size_t)r * Wc) = o;
        }
    }
}

extern "C" void kernel_launch(void* const* d_in, const int* in_sizes, int n_in,
                              void* d_out, int out_size, void* d_ws, size_t ws_size,
                              hipStream_t stream) {
    const float* x    = (const float*)d_in[0];
    const float* fc_w = (const float*)d_in[1];
    const float* fc_b = (const float*)d_in[2];
    const float* c1w  = (const float*)d_in[3];
    const float* c1b  = (const float*)d_in[4];
    const float* c2w  = (const float*)d_in[5];
    const float* c2b  = (const float*)d_in[6];
    // d_in[7] = size (int, ==4) -- shapes hardcoded to the reference.

    float* out = (float*)d_out;
    ciam_kernel<<<NPATCH / TP, 256, 0, stream>>>(x, fc_w, fc_b, c1w, c1b, c2w, c2b, out);
}

// Round 2
// 251.311 us; speedup vs baseline: 1.1095x; 1.1095x over previous
//
#include <hip/hip_runtime.h>
#include <math.h>

// Problem constants (reference shapes are fixed)
constexpr int Bc = 8, Cc = 64, Hc = 256, Wc = 256, Sc = 4;
constexpr int NPATCH = Bc * (Hc / Sc) * (Wc / Sc);  // 32768
constexpr int TP = 8;                               // patches per block (32-col strip)

// Tile T[c][r][col0..31]: float4-aligned pitches. CP % 32 == 20 -> for b128 ops each
// lane-octet's 4-bank spans cover all 32 banks (conflict-minimal per phase).
constexpr int RP = 36;                  // row pitch (32 data + 4 pad), mult of 4
constexpr int CP = 4 * RP + 4;          // 148
constexpr int TILE_F = Cc * CP;         // 9472 floats = 37888 B

// Overlays into S (tile is dead after the v-load barrier; both dead before write-back):
constexpr int FCW_P   = 66;             // even pitch -> float2 reads; 2-way banks (free)
constexpr int FCW_OFF = 0;              // 64*66 = 4224 floats
constexpr int PIX_P   = 68;             // mult-of-4 pitch -> b128 reads
constexpr int PIX_OFF = Cc * FCW_P;     // 4224
constexpr int PIX_W   = 16 * PIX_P;     // 1088 floats per wave
static_assert(PIX_OFF + 4 * PIX_W <= TILE_F, "overlay must fit inside tile");

__device__ __forceinline__ float sigmoidf_(float v) {
    return 1.0f / (1.0f + __expf(-v));
}

// 256 threads (4 waves), 8 patches/block. LDS = 37888 + 2048 = 39936 B -> 4 blocks/CU.
// 5 barriers: tile-ready, tile-consumed, fcw-ready, gates-done, writeback-done.
// Store-out is LDS-staged and fully coalesced (round-1's register-direct stores
// inflated WRITE_SIZE 45% -> reverted to staged).
__global__ __launch_bounds__(256, 4)
void ciam_kernel(const float* __restrict__ x,
                 const float* __restrict__ fc_w,
                 const float* __restrict__ fc_b,
                 const float* __restrict__ c1w,
                 const float* __restrict__ c1b,
                 const float* __restrict__ c2w,
                 const float* __restrict__ c2b,
                 float* __restrict__ out)
{
    __shared__ __align__(16) float S[TILE_F];        // tile; then fcw+pixbuf; then out-tile
    __shared__ __align__(16) float maxbuf[TP][64];   // per-patch channel maxes

    const int tid  = threadIdx.x;
    const int gid  = blockIdx.x;
    const int b    = gid >> 9;          // 512 blocks per batch (64 ph x 8 pwg)
    const int rem  = gid & 511;
    const int ph   = rem >> 3;
    const int pwg  = rem & 7;
    const int col0 = pwg * 32;

    // ---- Issue tile loads (coalesced float4; 8 in flight per thread) ----
    float4 tl[8];
    #pragma unroll
    for (int i = 0; i < 8; ++i) {
        const int u = i * 256 + tid;
        const int seg = u >> 3, c_ = seg >> 2, r_ = seg & 3, j4 = (u & 7) << 2;
        tl[i] = *reinterpret_cast<const float4*>(
            x + (((size_t)(b * Cc + c_) * Hc + (ph * Sc + r_)) * Wc + col0 + j4));
    }
    // ---- Prefetch fc_w into registers (ds-written after B2; latency hidden) ----
    float4 wl[4];
    #pragma unroll
    for (int i = 0; i < 4; ++i) {
        const int u = i * 256 + tid;
        const int row = u >> 4, jf = (u & 15) << 2;
        wl[i] = *reinterpret_cast<const float4*>(fc_w + row * 64 + jf);
    }
    const float fb  = fc_b[tid & 63];
    const float w10 = c1w[0], w11 = c1w[1], b1 = c1b[0];
    const float w20 = c2w[0], w21 = c2w[1], b2 = c2b[0];

    // ---- Tile -> LDS: one ds_write_b128 per iter, conflict-minimal ----
    #pragma unroll
    for (int i = 0; i < 8; ++i) {
        const int u = i * 256 + tid;
        const int seg = u >> 3, c_ = seg >> 2, r_ = seg & 3, j4 = (u & 7) << 2;
        *reinterpret_cast<float4*>(&S[c_ * CP + r_ * RP + j4]) = tl[i];
    }
    __syncthreads();                                   // B1: tile ready

    const int wave = tid >> 6, lane = tid & 63, c = lane;
    const int p0 = wave * 2;                           // this wave's two patches

    // ---- v-load: 8 x ds_read_b128 per lane (lane = channel) ----
    float v[2][16];
    #pragma unroll
    for (int pi = 0; pi < 2; ++pi) {
        const float* tp = &S[c * CP + (p0 + pi) * 4];
        #pragma unroll
        for (int r = 0; r < 4; ++r) {
            const float4 q4 = *reinterpret_cast<const float4*>(tp + r * RP);
            v[pi][r*4+0] = q4.x; v[pi][r*4+1] = q4.y;
            v[pi][r*4+2] = q4.z; v[pi][r*4+3] = q4.w;
        }
    }

    // ---- Channel attention input: per-channel max over patch pixels ----
    float mx0 = -3.4e38f, mx1 = -3.4e38f;
    #pragma unroll
    for (int t = 0; t < 16; ++t) {
        mx0 = fmaxf(mx0, v[0][t]);
        mx1 = fmaxf(mx1, v[1][t]);
    }
    maxbuf[p0][c]     = mx0;
    maxbuf[p0 + 1][c] = mx1;
    __syncthreads();                                   // B2: tile fully consumed, S reusable

    // ---- Overlay-stage fc_w (regs were loaded at kernel start) ----
    #pragma unroll
    for (int i = 0; i < 4; ++i) {
        const int u = i * 256 + tid;
        const int row = u >> 4, jf = (u & 15) << 2;
        float* fd = &S[FCW_OFF + row * FCW_P + jf];
        fd[0] = wl[i].x; fd[1] = wl[i].y; fd[2] = wl[i].z; fd[3] = wl[i].w;
    }
    __syncthreads();                                   // B3: fc_w ready

    // ---- FC (64x64 GEMV x2) -> sigmoid -> scale ----
    const float* wrow = &S[FCW_OFF + c * FCW_P];
    const float* m0r  = maxbuf[p0];
    const float* m1r  = maxbuf[p0 + 1];
    float a0 = fb, a1 = fb;
    #pragma unroll 8
    for (int k2 = 0; k2 < 32; ++k2) {
        const float2 wv = *reinterpret_cast<const float2*>(wrow + 2 * k2);
        const float2 q0 = *reinterpret_cast<const float2*>(m0r + 2 * k2);   // broadcast
        const float2 q1 = *reinterpret_cast<const float2*>(m1r + 2 * k2);   // broadcast
        a0 = fmaf(wv.x, q0.x, a0); a0 = fmaf(wv.y, q0.y, a0);
        a1 = fmaf(wv.x, q1.x, a1); a1 = fmaf(wv.y, q1.y, a1);
    }
    const float m0 = sigmoidf_(a0), m1 = sigmoidf_(a1);
    #pragma unroll
    for (int t = 0; t < 16; ++t) { v[0][t] *= m0; v[1][t] *= m1; }

    // ---- Per-pixel + per-patch gates (intra-wave; pixbuf is per-wave private) ----
    float* PB = &S[PIX_OFF + wave * PIX_W];
    const int a_ = lane >> 2, q_ = lane & 3;           // 4 lanes per pixel, 16 ch each
    const float* pbr = PB + a_ * PIX_P + q_ * 16;

    #pragma unroll
    for (int pi = 0; pi < 2; ++pi) {
        // pixel-major transpose (stride-1 writes, conflict-free)
        #pragma unroll
        for (int t = 0; t < 16; ++t)
            PB[t * PIX_P + c] = v[pi][t];
        __asm__ volatile("s_waitcnt lgkmcnt(0)" ::: "memory");  // wave-local fence

        float s = 0.f, mxp = -3.4e38f;
        #pragma unroll
        for (int t4 = 0; t4 < 4; ++t4) {
            const float4 u4 = *reinterpret_cast<const float4*>(pbr + 4 * t4);
            s += (u4.x + u4.y) + (u4.z + u4.w);
            mxp = fmaxf(mxp, fmaxf(fmaxf(u4.x, u4.y), fmaxf(u4.z, u4.w)));
        }
        s += __shfl_xor(s, 1);
        s += __shfl_xor(s, 2);
        mxp = fmaxf(mxp, __shfl_xor(mxp, 1));
        mxp = fmaxf(mxp, __shfl_xor(mxp, 2));
        const float g1 = sigmoidf_(w10 * (s * (1.f / 64.f)) + w11 * mxp + b1);

        // Patch gate directly from pixel stats: sum_a g1_a*s_a, max_a g1_a*mx_a (g1>0).
        float ts = g1 * s, tm = g1 * mxp;
        #pragma unroll
        for (int off = 4; off <= 32; off <<= 1) {
            ts += __shfl_xor(ts, off);
            tm  = fmaxf(tm, __shfl_xor(tm, off));
        }
        const float g2 = sigmoidf_(w20 * (ts * (1.f / 1024.f)) + w21 * tm + b2);

        // Apply per-pixel g1 (constant-lane shfl) and g2 in registers.
        #pragma unroll
        for (int t = 0; t < 16; ++t)
            v[pi][t] *= __shfl(g1, t << 2) * g2;
    }
    __syncthreads();                                   // B4: all gates done; overlays dead

    // ---- Write gated values back to tile (b128, conflict-minimal) ----
    #pragma unroll
    for (int pi = 0; pi < 2; ++pi) {
        float* tp = &S[c * CP + (p0 + pi) * 4];
        #pragma unroll
        for (int r = 0; r < 4; ++r) {
            float4 o;
            o.x = v[pi][r*4+0]; o.y = v[pi][r*4+1];
            o.z = v[pi][r*4+2]; o.w = v[pi][r*4+3];
            *reinterpret_cast<float4*>(tp + r * RP) = o;
        }
    }
    __syncthreads();                                   // B5: out-tile ready

    // ---- Stage-out: coalesced float4 stores (same mapping as stage-in) ----
    #pragma unroll
    for (int i = 0; i < 8; ++i) {
        const int u = i * 256 + tid;
        const int seg = u >> 3, c_ = seg >> 2, r_ = seg & 3, j4 = (u & 7) << 2;
        const float* ts = &S[c_ * CP + r_ * RP + j4];
        float4 o;
        o.x = ts[0]; o.y = ts[1]; o.z = ts[2]; o.w = ts[3];
        *reinterpret_cast<float4*>(
            out + (((size_t)(b * Cc + c_) * Hc + (ph * Sc + r_)) * Wc + col0 + j4)) = o;
    }
}

extern "C" void kernel_launch(void* const* d_in, const int* in_sizes, int n_in,
                              void* d_out, int out_size, void* d_ws, size_t ws_size,
                              hipStream_t stream) {
    const float* x    = (const float*)d_in[0];
    const float* fc_w = (const float*)d_in[1];
    const float* fc_b = (const float*)d_in[2];
    const float* c1w  = (const float*)d_in[3];
    const float* c1b  = (const float*)d_in[4];
    const float* c2w  = (const float*)d_in[5];
    const float* c2b  = (const float*)d_in[6];
    // d_in[7] = size (int, ==4) -- shapes hardcoded to the reference.

    float* out = (float*)d_out;
    ciam_kernel<<<NPATCH / TP, 256, 0, stream>>>(x, fc_w, fc_b, c1w, c1b, c2w, c2b, out);
}